// Round 2
// baseline (86.797 us; speedup 1.0000x reference)
//
#include <hip/hip_runtime.h>
#include <cmath>

// Problem constants (from reference)
constexpr int N_GAUSS = 16;
constexpr int N_GRAPHS = 64;
constexpr int K_GRID = 4096;

// Table parameters
constexpr int NSEG = 512;             // segments over r in [0, RMAX]
constexpr int TSTRIDE = 528;          // floats per atom row (513 used + pad, 16B-aligned)
constexpr float RMAX = 12.0f;         // r2 <= 144; P(r>12) ~ 1e-15 for these inputs

// Main kernel decomposition: per-graph ownership, atomic-free.
constexpr int TPB2 = 256;             // threads per block, 1 k-point per thread
constexpr int CHUNKS2 = K_GRID / TPB2;// 16 k-chunks per graph -> grid (16, 64) = 1024 blocks
constexpr int ATILE = 16;             // atoms staged per LDS tile (33,792 B)

struct GaussParams {
    float ns2[N_GAUSS]; // -log2(e)/sigma^2
    float b[N_GAUSS];   // log2(sigma_r)
};

__device__ __forceinline__ float fast_exp2(float x) {
    return __builtin_amdgcn_exp2f(x);
}

// ---- Kernel 1: per-atom radial table + graph boundary offsets ----
// grid = (2, n_atoms), block = 256.
__global__ __launch_bounds__(256) void build_table_kernel(
    const float* __restrict__ coeff,   // (N_ATOMS, 16)
    const int*   __restrict__ batch,   // (N_ATOMS,) sorted graph ids
    float* __restrict__ table,         // (N_ATOMS, TSTRIDE)
    int*   __restrict__ gstart,        // (N_GRAPHS+1,) graph start offsets
    GaussParams p, int n_atoms)
{
    const int a = blockIdx.y;
    const int t = (int)threadIdx.x;
    const int n = blockIdx.x * 256 + t;

    // Fused: 65 lanes binary-search the sorted batch array for graph boundaries.
    if (blockIdx.x == 0 && a == 0 && t <= N_GRAPHS) {
        const int g = t;
        int lo = 0, hi = n_atoms;
        while (lo < hi) {                       // lower_bound(batch, g)
            const int mid = (lo + hi) >> 1;
            if (batch[mid] < g) lo = mid + 1; else hi = mid;
        }
        gstart[t] = lo;
    }

    const float* __restrict__ cf = coeff + a * N_GAUSS; // wave-uniform -> s_load

    auto eval = [&](int idx) -> float {
        if (idx > NSEG) return 0.f;
        const float r = (float)idx * (RMAX / (float)NSEG);
        const float r2 = r * r;
        float a0 = 0.f, a1 = 0.f, a2 = 0.f, a3 = 0.f;
        #pragma unroll
        for (int g = 0; g < N_GAUSS; g += 4) {
            a0 = fmaf(cf[g + 0], fast_exp2(fmaf(r2, p.ns2[g + 0], p.b[g + 0])), a0);
            a1 = fmaf(cf[g + 1], fast_exp2(fmaf(r2, p.ns2[g + 1], p.b[g + 1])), a1);
            a2 = fmaf(cf[g + 2], fast_exp2(fmaf(r2, p.ns2[g + 2], p.b[g + 2])), a2);
            a3 = fmaf(cf[g + 3], fast_exp2(fmaf(r2, p.ns2[g + 3], p.b[g + 3])), a3);
        }
        return (a0 + a1) + (a2 + a3);
    };

    table[(size_t)a * TSTRIDE + n] = eval(n);
    if (blockIdx.x == 1 && t < TSTRIDE - 512) {
        const int n2 = 512 + t;
        table[(size_t)a * TSTRIDE + n2] = eval(n2);
    }
}

// ---- Kernel 2: per-graph gather + interp, atomic-free ----
// Each block owns out[g, chunk*256 .. chunk*256+255]: grid points live in
// registers for the whole kernel; atoms of graph g stream through LDS in
// tiles of ATILE; output written exactly once (no pre-zero, no atomics).
__global__ __launch_bounds__(TPB2, 4) void GaussianOrbital_kernel(
    const float* __restrict__ table,       // (N_ATOMS, TSTRIDE)
    const float* __restrict__ atom_coord,  // (N_ATOMS, 3)
    const float* __restrict__ grid,        // (N_GRAPHS, K_GRID, 3)
    const int*   __restrict__ gstart,      // (N_GRAPHS+1,)
    float* __restrict__ out)               // (N_GRAPHS, K_GRID)
{
    __shared__ float lds[ATILE * TSTRIDE];   // 33,792 B

    const int g = blockIdx.y;              // graph id
    const int t = (int)threadIdx.x;
    const int k = blockIdx.x * TPB2 + t;   // this thread's k-point

    const int s = __builtin_amdgcn_readfirstlane(gstart[g]);
    const int e = __builtin_amdgcn_readfirstlane(gstart[g + 1]);

    // Load my grid point once (coalesced: lanes read consecutive 12B triplets)
    const int b = (g * K_GRID + k) * 3;
    const float kx = grid[b + 0], ky = grid[b + 1], kz = grid[b + 2];

    float acc0 = 0.f, acc1 = 0.f;

    auto body = [&](const float* __restrict__ T,
                    float ax, float ay, float az, float& acc) {
        const float dx = kx - ax, dy = ky - ay, dz = kz - az;
        const float r2 = fmaf(dx, dx, fmaf(dy, dy, dz * dz));
        float tt = __builtin_amdgcn_sqrtf(r2) * ((float)NSEG / RMAX);
        tt = fminf(tt, (float)(NSEG - 1));
        const int i = (int)tt;             // tt >= 0: trunc == floor
        const float fr = tt - (float)i;
        const float f0 = T[i], f1 = T[i + 1];
        acc += fmaf(fr, f1 - f0, f0);
    };

    for (int a0 = s; a0 < e; a0 += ATILE) {
        const int na = min(ATILE, e - a0);

        __syncthreads();   // protect previous tile's LDS reads
        {
            const float4* __restrict__ src =
                (const float4*)(table + (size_t)a0 * TSTRIDE);
            float4* dst = (float4*)lds;
            const int nvec = na * (TSTRIDE / 4);
            for (int i = t; i < nvec; i += TPB2) dst[i] = src[i];
        }
        __syncthreads();

        if (na == ATILE) {
            // Full tile: hoist uniform coord loads, fully unroll 16 atoms
            float axs[ATILE], ays[ATILE], azs[ATILE];
            #pragma unroll
            for (int u = 0; u < ATILE; ++u) {
                const int a = a0 + u;
                axs[u] = atom_coord[a * 3 + 0];
                ays[u] = atom_coord[a * 3 + 1];
                azs[u] = atom_coord[a * 3 + 2];
            }
            #pragma unroll
            for (int u = 0; u < ATILE; ++u) {
                body(lds + u * TSTRIDE, axs[u], ays[u], azs[u],
                     (u & 1) ? acc1 : acc0);
            }
        } else {
            for (int u = 0; u < na; ++u) {
                const int a = a0 + u;
                body(lds + u * TSTRIDE,
                     atom_coord[a * 3 + 0], atom_coord[a * 3 + 1],
                     atom_coord[a * 3 + 2], (u & 1) ? acc1 : acc0);
            }
        }
    }

    // Exactly one writer per (g, k): plain store, no pre-zero needed.
    out[g * K_GRID + k] = acc0 + acc1;
}

extern "C" void kernel_launch(void* const* d_in, const int* in_sizes, int n_in,
                              void* d_out, int out_size, void* d_ws, size_t ws_size,
                              hipStream_t stream)
{
    const float* coeff      = (const float*)d_in[0];
    const float* atom_coord = (const float*)d_in[1];
    const float* grid       = (const float*)d_in[2];
    const int*   batch      = (const int*)d_in[3];
    float* out   = (float*)d_out;
    float* table = (float*)d_ws;           // n_atoms * 528 * 4B = 6.49 MB
    const int n_atoms = in_sizes[0] / N_GAUSS;
    int* gstart = (int*)(table + (size_t)n_atoms * TSTRIDE);  // 65 ints after table

    GaussParams p;
    const double sqrt2pi = 2.50662827463100050242;
    for (int g = 0; g < N_GAUSS; ++g) {
        const double sigma = 0.5 + (5.0 - 0.5) * (double)g / (double)(N_GAUSS - 1);
        p.ns2[g] = (float)(-1.44269504088896340736 / (sigma * sigma));
        const double sr = 1.0 / (sigma * sqrt2pi * sigma * sqrt2pi * sigma * sqrt2pi);
        p.b[g] = (float)(std::log2(sr));
    }

    // 1) build per-atom radial tables + graph boundary offsets
    {
        dim3 gDim(2, n_atoms);
        hipLaunchKernelGGL(build_table_kernel, gDim, dim3(256), 0, stream,
                           coeff, batch, table, gstart, p, n_atoms);
    }
    // 2) main per-graph gather/interp kernel (atomic-free, store-once)
    {
        dim3 gDim(CHUNKS2, N_GRAPHS);
        hipLaunchKernelGGL(GaussianOrbital_kernel, gDim, dim3(TPB2), 0, stream,
                           table, atom_coord, grid, gstart, out);
    }
}

// Round 3
// 81.329 us; speedup vs baseline: 1.0672x; 1.0672x over previous
//
#include <hip/hip_runtime.h>
#include <cmath>

// Problem constants (from reference)
constexpr int N_GAUSS = 16;
constexpr int N_GRAPHS = 64;
constexpr int K_GRID = 4096;

// Table parameters
constexpr int NSEG = 512;             // segments over r in [0, RMAX]
constexpr int TSTRIDE = 528;          // floats per atom row (513 used + pad, 16B-aligned)
constexpr float RMAX = 12.0f;         // r2 <= 144; P(r>12) ~ 1e-15 for these inputs

// Main kernel decomposition
constexpr int KCHUNK = 256;           // threads per block
constexpr int KPER = 4;               // k-points per thread (independent chains for ILP)
constexpr int KSPAN = KCHUNK * KPER;  // 1024
constexpr int CHUNKS = K_GRID / KSPAN;// 4
constexpr int APB = 8;                // atoms per block -> LDS 16.9 KB
// grid = (4, 384) = 1536 blocks = exactly 6 blocks/CU on 256 CUs, zero tail.

struct GaussParams {
    float ns2[N_GAUSS]; // -log2(e)/sigma^2
    float b[N_GAUSS];   // log2(sigma_r)
};

__device__ __forceinline__ float fast_exp2(float x) {
    return __builtin_amdgcn_exp2f(x);
}

// ---- Kernel 1: per-atom radial table + fused zeroing of out ----
// grid = (2, n_atoms), block = 256.
__global__ __launch_bounds__(256) void build_table_kernel(
    const float* __restrict__ coeff,   // (N_ATOMS, 16)
    float* __restrict__ table,         // (N_ATOMS, TSTRIDE)
    float* __restrict__ out,           // (N_GRAPHS*K_GRID) -- zeroed here
    GaussParams p)
{
    const int a = blockIdx.y;
    const int t = (int)threadIdx.x;
    const int n = blockIdx.x * 256 + t;

    // Fused zero-init of out: blocks (bx==0, a<256) cover 256*256 float4 = 1 MB
    if (blockIdx.x == 0 && a < (N_GRAPHS * K_GRID) / (256 * 4)) {
        ((float4*)out)[a * 256 + t] = make_float4(0.f, 0.f, 0.f, 0.f);
    }

    const float* __restrict__ cf = coeff + a * N_GAUSS; // wave-uniform -> s_load

    auto eval = [&](int idx) -> float {
        if (idx > NSEG) return 0.f;
        const float r = (float)idx * (RMAX / (float)NSEG);
        const float r2 = r * r;
        float a0 = 0.f, a1 = 0.f, a2 = 0.f, a3 = 0.f;
        #pragma unroll
        for (int g = 0; g < N_GAUSS; g += 4) {
            a0 = fmaf(cf[g + 0], fast_exp2(fmaf(r2, p.ns2[g + 0], p.b[g + 0])), a0);
            a1 = fmaf(cf[g + 1], fast_exp2(fmaf(r2, p.ns2[g + 1], p.b[g + 1])), a1);
            a2 = fmaf(cf[g + 2], fast_exp2(fmaf(r2, p.ns2[g + 2], p.b[g + 2])), a2);
            a3 = fmaf(cf[g + 3], fast_exp2(fmaf(r2, p.ns2[g + 3], p.b[g + 3])), a3);
        }
        return (a0 + a1) + (a2 + a3);
    };

    table[(size_t)a * TSTRIDE + n] = eval(n);
    if (blockIdx.x == 1 && t < TSTRIDE - 512) {
        const int n2 = 512 + t;
        table[(size_t)a * TSTRIDE + n2] = eval(n2);
    }
}

// ---- Kernel 2: gather + interp, 4 k-points per thread ----
// APB=8 (16.9 KB LDS) + __launch_bounds__(256,6): 6 blocks/CU resident
// (24 waves/CU vs 16 before) to hide the ~120-cyc LDS gather latency.
// Coord loads stay wave-uniform (s_load path, zero VGPR cost); no hoisted
// per-atom register arrays so the VGPR cap holds without spills.
__global__ __launch_bounds__(KCHUNK, 6) void GaussianOrbital_kernel(
    const float* __restrict__ table,       // (N_ATOMS, TSTRIDE)
    const float* __restrict__ atom_coord,  // (N_ATOMS, 3)
    const float* __restrict__ grid,        // (N_GRAPHS, K_GRID, 3)
    const int* __restrict__ batch,         // (N_ATOMS,) sorted graph ids
    float* __restrict__ out,               // (N_GRAPHS, K_GRID), pre-zeroed by build
    int n_atoms)
{
    __shared__ float lds[APB * TSTRIDE];   // 16,896 B

    const int chunk = blockIdx.x;          // 0..CHUNKS-1
    const int ablk  = blockIdx.y;          // 0..(n_atoms/APB)-1
    const int t = (int)threadIdx.x;

    const int lo = ablk * APB;
    int hi = lo + APB; if (hi > n_atoms) hi = n_atoms;

    // Stage this block's atom tables into LDS (contiguous, vectorized)
    {
        const float4* __restrict__ src = (const float4*)(table + (size_t)lo * TSTRIDE);
        float4* dst = (float4*)lds;
        const int nvec = (hi - lo) * TSTRIDE / 4;   // 1056 for full blocks
        #pragma unroll 2
        for (int i = t; i < nvec; i += KCHUNK) dst[i] = src[i];
    }
    __syncthreads();

    float kx[KPER], ky[KPER], kz[KPER], acc[KPER];
    auto load_grid = [&](int g) {
        #pragma unroll
        for (int j = 0; j < KPER; ++j) {
            const int k = chunk * KSPAN + j * KCHUNK + t;
            const int b = (g * K_GRID + k) * 3;
            kx[j] = grid[b + 0]; ky[j] = grid[b + 1]; kz[j] = grid[b + 2];
        }
    };
    auto flush = [&](int g) {
        #pragma unroll
        for (int j = 0; j < KPER; ++j) {
            const int k = chunk * KSPAN + j * KCHUNK + t;
            atomicAdd(&out[g * K_GRID + k], acc[j]);
            acc[j] = 0.f;
        }
    };
    // One atom's contribution against the staged table row T.
    auto body = [&](int a, const float* __restrict__ T) {
        // wave-uniform scalar loads (constant-cache/SGPR path)
        const float ax = atom_coord[a * 3 + 0];
        const float ay = atom_coord[a * 3 + 1];
        const float az = atom_coord[a * 3 + 2];
        float fr[KPER]; int ii[KPER];
        #pragma unroll
        for (int j = 0; j < KPER; ++j) {
            const float dx = kx[j] - ax, dy = ky[j] - ay, dz = kz[j] - az;
            const float r2 = fmaf(dx, dx, fmaf(dy, dy, dz * dz));
            float tt = __builtin_amdgcn_sqrtf(r2) * ((float)NSEG / RMAX);
            tt = fminf(tt, (float)(NSEG - 1));
            const int i = (int)tt;            // tt >= 0: trunc == floor
            fr[j] = tt - (float)i;
            ii[j] = i;
        }
        float f0[KPER], f1[KPER];
        #pragma unroll
        for (int j = 0; j < KPER; ++j) { f0[j] = T[ii[j]]; f1[j] = T[ii[j] + 1]; }
        #pragma unroll
        for (int j = 0; j < KPER; ++j) acc[j] = acc[j] + fmaf(fr[j], f1[j] - f0[j], f0[j]);
    };

    int cur_g = __builtin_amdgcn_readfirstlane(batch[lo]);
    load_grid(cur_g);
    #pragma unroll
    for (int j = 0; j < KPER; ++j) acc[j] = 0.f;

    const bool full = (hi - lo) == APB;
    const int last_g = __builtin_amdgcn_readfirstlane(batch[hi - 1]);

    if (full && last_g == cur_g) {
        // Uniform-graph fast path (~84% of blocks): straight-line unroll,
        // all 8 atoms' gathers visible to the scheduler as independent chains.
        #pragma unroll
        for (int u = 0; u < APB; ++u) body(lo + u, lds + u * TSTRIDE);
        flush(cur_g);
    } else {
        // General path: graph boundary inside block (or tail block)
        for (int a = lo; a < hi; ++a) {
            const int g = __builtin_amdgcn_readfirstlane(batch[a]);
            if (g != cur_g) {            // wave-uniform branch
                flush(cur_g);
                cur_g = g;
                load_grid(cur_g);
            }
            body(a, lds + (a - lo) * TSTRIDE);
        }
        flush(cur_g);
    }
}

extern "C" void kernel_launch(void* const* d_in, const int* in_sizes, int n_in,
                              void* d_out, int out_size, void* d_ws, size_t ws_size,
                              hipStream_t stream)
{
    const float* coeff      = (const float*)d_in[0];
    const float* atom_coord = (const float*)d_in[1];
    const float* grid       = (const float*)d_in[2];
    const int*   batch      = (const int*)d_in[3];
    float* out   = (float*)d_out;
    float* table = (float*)d_ws;           // n_atoms * 528 * 4B = 6.49 MB
    const int n_atoms = in_sizes[0] / N_GAUSS;

    GaussParams p;
    const double sqrt2pi = 2.50662827463100050242;
    for (int g = 0; g < N_GAUSS; ++g) {
        const double sigma = 0.5 + (5.0 - 0.5) * (double)g / (double)(N_GAUSS - 1);
        p.ns2[g] = (float)(-1.44269504088896340736 / (sigma * sigma));
        const double sr = 1.0 / (sigma * sqrt2pi * sigma * sqrt2pi * sigma * sqrt2pi);
        p.b[g] = (float)(std::log2(sr));
    }

    // 1) build per-atom radial tables + fused zero of out
    {
        dim3 gDim(2, n_atoms);
        hipLaunchKernelGGL(build_table_kernel, gDim, dim3(256), 0, stream,
                           coeff, table, out, p);
    }
    // 2) main gather/interp kernel
    {
        const int n_ablk = (n_atoms + APB - 1) / APB;   // 384
        dim3 gDim(CHUNKS, n_ablk);
        hipLaunchKernelGGL(GaussianOrbital_kernel, gDim, dim3(KCHUNK), 0, stream,
                           table, atom_coord, grid, batch, out, n_atoms);
    }
}